// Round 9
// baseline (239.194 us; speedup 1.0000x reference)
//
#include <hip/hip_runtime.h>
#include <hip/hip_bf16.h>
#include <math.h>

// x: [D=32, N=9216] fp32. 3 iters: w(i,j)=exp(3*<x_i,x_j>),
// x[:,j] <- 0.5*sum_i w*x[:,i]/sum_i w + 0.5*x[:,j]
// Output: [x3][x1][x2][x3].
// R9 PROBE ROUND: real path = R8 barrier-free accum (A) + R3-style coalesced
// combine. Two probe dispatches to dummy ws isolate the accum bottleneck:
//   B = A with exp->multiply  (tests transcendental pipe)
//   C = A with QK->PV chain cut (tests MFMA<->VALU cross-pipe latency)

#define D 32
#define NPIX 9216
#define NSPLIT 16            // i-split
#define JB 128               // j per block = 2 waves * 64 j
#define NJB 72               // NPIX/JB
#define IPB 576              // NPIX/NSPLIT
#define NBLK 1152            // NJB*NSPLIT
#define NTHR 128
#define TS  40               // combine transpose tile stride (shorts)

typedef __attribute__((ext_vector_type(8))) short short8;
typedef __attribute__((ext_vector_type(4))) float f32x4;

#if __has_builtin(__builtin_amdgcn_exp2f)
#define EXP2F __builtin_amdgcn_exp2f
#else
#define EXP2F exp2f
#endif

#define C3 4.32808512266689f   // 3 * log2(e)

__device__ __forceinline__ unsigned pack2_bf16(float a, float b) {
    union { __hip_bfloat162 h2; unsigned u; } c;
    c.h2 = __float22bfloat162_rn(make_float2(a, b));
    return c.u;
}
__device__ __forceinline__ short pack1_bf16(float a) {
    union { __hip_bfloat16 h; unsigned short s; } c;
    c.h = __float2bfloat16(a);
    return (short)c.s;
}

// ---------------- A: real accum (R8 barrier-free, no LDS) --------------------
__global__ __launch_bounds__(NTHR) void accum_kernel(
    const short* __restrict__ xb, const short* __restrict__ xbT,
    float* __restrict__ num_part, float* __restrict__ den_part)
{
    const int t = threadIdx.x;
    const int wid = t >> 6, lane = t & 63, quad = lane >> 4, m = lane & 15;
    const int bj = blockIdx.x % NJB, bi = blockIdx.x / NJB;
    const int j0 = bj * JB + wid * 64;
    const int i0b = bi * IPB;

    short8 bfrag[4];
#pragma unroll
    for (int jt = 0; jt < 4; ++jt)
        bfrag[jt] = *(const short8*)&xbT[(size_t)(j0 + jt * 16 + m) * D + quad * 8];

    f32x4 acc[2][4] = {};
    float dacc[4] = {0.f, 0.f, 0.f, 0.f};

    const int sinv = ((m & 12) << 1) | (m & 3);
    const short* pT = xbT + (size_t)(i0b + sinv) * D + quad * 8;
    const short* pV = xb + (size_t)m * NPIX + i0b + quad * 8;

    short8 cT0 = *(const short8*)pT;
    short8 cT1 = *(const short8*)(pT + 4 * D);
    short8 cV0 = *(const short8*)pV;
    short8 cV1 = *(const short8*)(pV + 16 * NPIX);

    for (int c = 0; c < IPB / 32; ++c) {
        short8 nT0 = cT0, nT1 = cT1, nV0 = cV0, nV1 = cV1;
        if (c + 1 < IPB / 32) {
            const short* qT = pT + (size_t)(c + 1) * 32 * D;
            const short* qV = pV + (c + 1) * 32;
            nT0 = *(const short8*)qT;
            nT1 = *(const short8*)(qT + 4 * D);
            nV0 = *(const short8*)qV;
            nV1 = *(const short8*)(qV + 16 * NPIX);
        }
#pragma unroll
        for (int jt = 0; jt < 4; ++jt) {
            f32x4 z = {0.f, 0.f, 0.f, 0.f};
            f32x4 s0 = __builtin_amdgcn_mfma_f32_16x16x32_bf16(cT0, bfrag[jt], z, 0, 0, 0);
            f32x4 s1 = __builtin_amdgcn_mfma_f32_16x16x32_bf16(cT1, bfrag[jt], z, 0, 0, 0);
            float w[8];
#pragma unroll
            for (int r = 0; r < 4; ++r) { w[r]     = EXP2F(C3 * s0[r]);
                                          w[4 + r] = EXP2F(C3 * s1[r]); }
            dacc[jt] += ((w[0]+w[1])+(w[2]+w[3])) + ((w[4]+w[5])+(w[6]+w[7]));
            union { short8 s; unsigned u[4]; } wb;
            wb.u[0] = pack2_bf16(w[0], w[1]);
            wb.u[1] = pack2_bf16(w[2], w[3]);
            wb.u[2] = pack2_bf16(w[4], w[5]);
            wb.u[3] = pack2_bf16(w[6], w[7]);
            acc[0][jt] = __builtin_amdgcn_mfma_f32_16x16x32_bf16(cV0, wb.s, acc[0][jt], 0, 0, 0);
            acc[1][jt] = __builtin_amdgcn_mfma_f32_16x16x32_bf16(cV1, wb.s, acc[1][jt], 0, 0, 0);
        }
        cT0 = nT0; cT1 = nT1; cV0 = nV0; cV1 = nV1;
    }

    float* np = num_part + (size_t)bi * D * NPIX;
#pragma unroll
    for (int dt = 0; dt < 2; ++dt)
#pragma unroll
        for (int jt = 0; jt < 4; ++jt)
#pragma unroll
            for (int r = 0; r < 4; ++r)
                np[(dt * 16 + quad * 4 + r) * NPIX + j0 + jt * 16 + m] = acc[dt][jt][r];
#pragma unroll
    for (int jt = 0; jt < 4; ++jt) {
        float v = dacc[jt];
        v += __shfl_xor(v, 16, 64);
        v += __shfl_xor(v, 32, 64);
        if (quad == 0) den_part[bi * NPIX + j0 + jt * 16 + m] = v;
    }
}

// ---------------- B: probe — exp replaced by multiply ------------------------
__global__ __launch_bounds__(NTHR) void accum_noexp_kernel(
    const short* __restrict__ xb, const short* __restrict__ xbT,
    float* __restrict__ num_part, float* __restrict__ den_part)
{
    const int t = threadIdx.x;
    const int wid = t >> 6, lane = t & 63, quad = lane >> 4, m = lane & 15;
    const int bj = blockIdx.x % NJB, bi = blockIdx.x / NJB;
    const int j0 = bj * JB + wid * 64;
    const int i0b = bi * IPB;

    short8 bfrag[4];
#pragma unroll
    for (int jt = 0; jt < 4; ++jt)
        bfrag[jt] = *(const short8*)&xbT[(size_t)(j0 + jt * 16 + m) * D + quad * 8];

    f32x4 acc[2][4] = {};
    float dacc[4] = {0.f, 0.f, 0.f, 0.f};

    const int sinv = ((m & 12) << 1) | (m & 3);
    const short* pT = xbT + (size_t)(i0b + sinv) * D + quad * 8;
    const short* pV = xb + (size_t)m * NPIX + i0b + quad * 8;

    short8 cT0 = *(const short8*)pT;
    short8 cT1 = *(const short8*)(pT + 4 * D);
    short8 cV0 = *(const short8*)pV;
    short8 cV1 = *(const short8*)(pV + 16 * NPIX);

    for (int c = 0; c < IPB / 32; ++c) {
        short8 nT0 = cT0, nT1 = cT1, nV0 = cV0, nV1 = cV1;
        if (c + 1 < IPB / 32) {
            const short* qT = pT + (size_t)(c + 1) * 32 * D;
            const short* qV = pV + (c + 1) * 32;
            nT0 = *(const short8*)qT;
            nT1 = *(const short8*)(qT + 4 * D);
            nV0 = *(const short8*)qV;
            nV1 = *(const short8*)(qV + 16 * NPIX);
        }
#pragma unroll
        for (int jt = 0; jt < 4; ++jt) {
            f32x4 z = {0.f, 0.f, 0.f, 0.f};
            f32x4 s0 = __builtin_amdgcn_mfma_f32_16x16x32_bf16(cT0, bfrag[jt], z, 0, 0, 0);
            f32x4 s1 = __builtin_amdgcn_mfma_f32_16x16x32_bf16(cT1, bfrag[jt], z, 0, 0, 0);
            float w[8];
#pragma unroll
            for (int r = 0; r < 4; ++r) { w[r]     = C3 * s0[r];     // NO exp
                                          w[4 + r] = C3 * s1[r]; }
            dacc[jt] += ((w[0]+w[1])+(w[2]+w[3])) + ((w[4]+w[5])+(w[6]+w[7]));
            union { short8 s; unsigned u[4]; } wb;
            wb.u[0] = pack2_bf16(w[0], w[1]);
            wb.u[1] = pack2_bf16(w[2], w[3]);
            wb.u[2] = pack2_bf16(w[4], w[5]);
            wb.u[3] = pack2_bf16(w[6], w[7]);
            acc[0][jt] = __builtin_amdgcn_mfma_f32_16x16x32_bf16(cV0, wb.s, acc[0][jt], 0, 0, 0);
            acc[1][jt] = __builtin_amdgcn_mfma_f32_16x16x32_bf16(cV1, wb.s, acc[1][jt], 0, 0, 0);
        }
        cT0 = nT0; cT1 = nT1; cV0 = nV0; cV1 = nV1;
    }

    float* np = num_part + (size_t)bi * D * NPIX;
#pragma unroll
    for (int dt = 0; dt < 2; ++dt)
#pragma unroll
        for (int jt = 0; jt < 4; ++jt)
#pragma unroll
            for (int r = 0; r < 4; ++r)
                np[(dt * 16 + quad * 4 + r) * NPIX + j0 + jt * 16 + m] = acc[dt][jt][r];
#pragma unroll
    for (int jt = 0; jt < 4; ++jt) {
        float v = dacc[jt];
        v += __shfl_xor(v, 16, 64);
        v += __shfl_xor(v, 32, 64);
        if (quad == 0) den_part[bi * NPIX + j0 + jt * 16 + m] = v;
    }
}

// ---------------- C: probe — QK->PV cross-pipe chain cut ---------------------
__global__ __launch_bounds__(NTHR) void accum_nochain_kernel(
    const short* __restrict__ xb, const short* __restrict__ xbT,
    float* __restrict__ num_part, float* __restrict__ den_part)
{
    const int t = threadIdx.x;
    const int wid = t >> 6, lane = t & 63, quad = lane >> 4, m = lane & 15;
    const int bj = blockIdx.x % NJB, bi = blockIdx.x / NJB;
    const int j0 = bj * JB + wid * 64;
    const int i0b = bi * IPB;

    short8 bfrag[4];
#pragma unroll
    for (int jt = 0; jt < 4; ++jt)
        bfrag[jt] = *(const short8*)&xbT[(size_t)(j0 + jt * 16 + m) * D + quad * 8];

    f32x4 acc[2][4] = {};
    float dacc[4] = {0.f, 0.f, 0.f, 0.f};

    const int sinv = ((m & 12) << 1) | (m & 3);
    const short* pT = xbT + (size_t)(i0b + sinv) * D + quad * 8;
    const short* pV = xb + (size_t)m * NPIX + i0b + quad * 8;

    short8 cT0 = *(const short8*)pT;
    short8 cT1 = *(const short8*)(pT + 4 * D);
    short8 cV0 = *(const short8*)pV;
    short8 cV1 = *(const short8*)(pV + 16 * NPIX);

    for (int c = 0; c < IPB / 32; ++c) {
        short8 nT0 = cT0, nT1 = cT1, nV0 = cV0, nV1 = cV1;
        if (c + 1 < IPB / 32) {
            const short* qT = pT + (size_t)(c + 1) * 32 * D;
            const short* qV = pV + (c + 1) * 32;
            nT0 = *(const short8*)qT;
            nT1 = *(const short8*)(qT + 4 * D);
            nV0 = *(const short8*)qV;
            nV1 = *(const short8*)(qV + 16 * NPIX);
        }
#pragma unroll
        for (int jt = 0; jt < 4; ++jt) {
            f32x4 z = {0.f, 0.f, 0.f, 0.f};
            f32x4 s0 = __builtin_amdgcn_mfma_f32_16x16x32_bf16(cT0, bfrag[jt], z, 0, 0, 0);
            f32x4 s1 = __builtin_amdgcn_mfma_f32_16x16x32_bf16(cT1, bfrag[jt], z, 0, 0, 0);
            dacc[jt] += s0[0] + s1[0];   // minimal read keeps QK alive
            // PV consumes resident fragment — no exp, no pack, no cross-pipe dep
            acc[0][jt] = __builtin_amdgcn_mfma_f32_16x16x32_bf16(cV0, bfrag[jt], acc[0][jt], 0, 0, 0);
            acc[1][jt] = __builtin_amdgcn_mfma_f32_16x16x32_bf16(cV1, bfrag[jt], acc[1][jt], 0, 0, 0);
        }
        cT0 = nT0; cT1 = nT1; cV0 = nV0; cV1 = nV1;
    }

    float* np = num_part + (size_t)bi * D * NPIX;
#pragma unroll
    for (int dt = 0; dt < 2; ++dt)
#pragma unroll
        for (int jt = 0; jt < 4; ++jt)
#pragma unroll
            for (int r = 0; r < 4; ++r)
                np[(dt * 16 + quad * 4 + r) * NPIX + j0 + jt * 16 + m] = acc[dt][jt][r];
#pragma unroll
    for (int jt = 0; jt < 4; ++jt) {
        float v = dacc[jt];
        v += __shfl_xor(v, 16, 64);
        v += __shfl_xor(v, 32, 64);
        if (quad == 0) den_part[bi * NPIX + j0 + jt * 16 + m] = v;
    }
}

// ---------------- combine (R3-style, coalesced) ------------------------------
__global__ __launch_bounds__(256) void combine_kernel(
    const float* __restrict__ xin,
    const float* __restrict__ num_part, const float* __restrict__ den_part,
    float* __restrict__ xout, float* __restrict__ xfinal,
    short* __restrict__ xb, short* __restrict__ xbT, int do_ms)
{
    __shared__ __align__(16) short tile[64 * TS];   // [i_local][d]
    const int t = threadIdx.x;
    const int il = t & 63, q = t >> 6;
    const int i = blockIdx.x * 64 + il;
    const int d0 = q * 8;

    float inv = 0.f;
    if (do_ms) {
        float den = 0.f;
#pragma unroll
        for (int s = 0; s < NSPLIT; ++s) den += den_part[s * NPIX + i];
        inv = 0.5f / den;
    }

#pragma unroll
    for (int dd = 0; dd < 8; ++dd) {
        const int d = d0 + dd;
        const int idx = d * NPIX + i;
        float v;
        if (do_ms) {
            float nm = 0.f;
#pragma unroll
            for (int s = 0; s < NSPLIT; ++s) nm += num_part[(s * D + d) * NPIX + i];
            v = nm * inv + 0.5f * xin[idx];
            xout[idx] = v;
            if (xfinal) xfinal[idx] = v;
        } else {
            v = xin[idx];
        }
        short b = pack1_bf16(v);
        xb[idx] = b;
        tile[il * TS + d] = b;
    }
    __syncthreads();
    *(short8*)&xbT[(size_t)i * D + d0] = *(const short8*)&tile[il * TS + d0];
}

extern "C" void kernel_launch(void* const* d_in, const int* in_sizes, int n_in,
                              void* d_out, int out_size, void* d_ws, size_t ws_size,
                              hipStream_t stream)
{
    const float* x0 = (const float*)d_in[0];
    float* out = (float*)d_out;              // [x3][x1][x2][x3]
    const size_t slot = (size_t)D * NPIX;

    float* num_part = (float*)d_ws;                          // 18.9 MB
    float* den_part = num_part + (size_t)NSPLIT * slot;      // 590 KB
    short* xb  = (short*)(den_part + (size_t)NSPLIT * NPIX); // 590 KB
    short* xbT = xb + slot;                                  // 590 KB
    float* dummy_np = (float*)(xbT + slot);                  // probe sink 18.9 MB
    float* dummy_dp = dummy_np + (size_t)NSPLIT * slot;      // probe sink

    // convert x0 -> xb/xbT
    combine_kernel<<<dim3(NPIX / 64), dim3(256), 0, stream>>>(
        x0, nullptr, nullptr, nullptr, nullptr, xb, xbT, 0);

    // --- probes (results discarded; same every call, graph-safe) ---
    accum_noexp_kernel<<<dim3(NBLK), dim3(NTHR), 0, stream>>>(
        xb, xbT, dummy_np, dummy_dp);
    accum_nochain_kernel<<<dim3(NBLK), dim3(NTHR), 0, stream>>>(
        xb, xbT, dummy_np, dummy_dp);

    // --- real path ---
    for (int it = 0; it < 3; ++it) {
        accum_kernel<<<dim3(NBLK), dim3(NTHR), 0, stream>>>(
            xb, xbT, num_part, den_part);
        const float* xin = (it == 0) ? x0 : (out + (size_t)it * slot);
        combine_kernel<<<dim3(NPIX / 64), dim3(256), 0, stream>>>(
            xin, num_part, den_part, out + (size_t)(it + 1) * slot,
            (it == 2) ? out : nullptr, xb, xbT, 1);
    }
}